// Round 8
// baseline (220.744 us; speedup 1.0000x reference)
//
#include <hip/hip_runtime.h>
#include <stdint.h>

// B=16, CIN=512, COUT=128, H=W=64
#define NB    16
#define CIN   512
#define COUT  128
#define HW    4096
#define BN    128             // N-tile per block-job
#define BK    32              // K-tile per iteration
#define NIT   (CIN / BK)      // 16
#define NJOBS 512             // 16 b x 32 n-tiles
// grid = 256 blocks x 512 thr, each block runs 2 jobs sequentially (persistent)

using bf16x8  = __attribute__((ext_vector_type(8))) __bf16;
using floatx4 = __attribute__((ext_vector_type(4))) float;

// RNE float -> bf16 bits (proven R1-R7)
__device__ __forceinline__ unsigned short f2bf_bits(float f) {
    union { float f; unsigned u; } v; v.f = f;
    return (unsigned short)((v.u + 0x7fffu + ((v.u >> 16) & 1u)) >> 16);
}

// async global->LDS, 16B/lane; LDS dest = wave-uniform base + lane*16
#define GLD16(g, l)                                                            \
    __builtin_amdgcn_global_load_lds(                                          \
        (const __attribute__((address_space(1))) void*)(g),                    \
        (__attribute__((address_space(3))) void*)(l), 16, 0, 0)

// ---------------------------------------------------------------------------
// Precompute mw[b][k8][m][j] = bf16(weight[m][k8*8+j] * style[b][k8*8+j])
// = the 16x16x32 A-fragment layout, contiguous 8KB slab per K-tile.
// ---------------------------------------------------------------------------
__global__ __launch_bounds__(256)
void modw_kernel(const float* __restrict__ style,
                 const float* __restrict__ weight,
                 __bf16* __restrict__ mw)
{
    const int id = blockIdx.x * 256 + threadIdx.x;   // 512 blocks
    const int k8 = id & 63;
    const int m  = (id >> 6) & 127;
    const int b  = id >> 13;

    const float4 w0 = *(const float4*)(weight + m * CIN + k8 * 8);
    const float4 w1 = *(const float4*)(weight + m * CIN + k8 * 8 + 4);
    const float4 s0 = *(const float4*)(style + b * CIN + k8 * 8);
    const float4 s1 = *(const float4*)(style + b * CIN + k8 * 8 + 4);

    union { unsigned short us[8]; bf16x8 v; } pk;
    pk.us[0] = f2bf_bits(w0.x * s0.x);
    pk.us[1] = f2bf_bits(w0.y * s0.y);
    pk.us[2] = f2bf_bits(w0.z * s0.z);
    pk.us[3] = f2bf_bits(w0.w * s0.w);
    pk.us[4] = f2bf_bits(w1.x * s1.x);
    pk.us[5] = f2bf_bits(w1.y * s1.y);
    pk.us[6] = f2bf_bits(w1.z * s1.z);
    pk.us[7] = f2bf_bits(w1.w * s1.w);
    *(bf16x8*)(mw + ((size_t)(b * 64 + k8) * 128 + m) * 8) = pk.v;
}

// ---------------------------------------------------------------------------
// DIAGNOSTIC persistent variant of R6: grid 256 (1 block/CU), 2 jobs/block.
// Per job: 128x128 tile, 8 waves of 64x32, dbuf LDS, 1 barrier/iter,
// all global reads via global_load_lds (A: 16B/lane; B: 1KB/instr).
// Goal: push kernel duration above the 79us fill cutoff so rocprof top-5
// finally shows OUR counters (FETCH_SIZE / VALUBusy / MfmaUtil / Occupancy).
// ---------------------------------------------------------------------------
__global__ __launch_bounds__(512, 4)
void modconv1x1_kernel(const float* __restrict__ x,
                       const __bf16* __restrict__ mw,
                       float* __restrict__ out)
{
    __shared__ __align__(16) __bf16 Alds[2][4096];      // [k8][m][j]  2 x 8 KB
    __shared__ __align__(16) float  Blds[2][BK * BN];   // [k][n]      2 x 16 KB

    const int tid  = threadIdx.x;
    const int lane = tid & 63;
    const int wave = tid >> 6;          // 0..7
    const int quad = lane >> 4;
    const int l15  = lane & 15;

    const int wm = (wave & 1) * 64;     // wave tile 64(m) x 32(n)
    const int wn = (wave >> 1) * 32;

    // B GLD geometry: instr g covers rows 2g,2g+1 (512B each)
    const int brsel = lane >> 5;        // which of the two rows
    const int bcol  = lane & 31;        // float4 column within row

    #pragma unroll 1
    for (int jj = 0; jj < 2; ++jj) {
        const int job = blockIdx.x + jj * 256;      // 0..511
        const int b   = job >> 5;
        const int n0  = (job & 31) * BN;

        const char*  xbb  = (const char*)(x + (size_t)b * CIN * HW + n0);
        float*       outb = out + (size_t)b * COUT * HW + n0;
        const char*  mwb  = (const char*)mw + (size_t)b * (64 * 128 * 16);

        floatx4 acc[4][2];
        #pragma unroll
        for (int i = 0; i < 4; ++i)
            #pragma unroll
            for (int j = 0; j < 2; ++j)
                acc[i][j] = (floatx4){0.f, 0.f, 0.f, 0.f};

#define STAGE(K0, BUF)                                                         \
    {                                                                          \
        const char* at = mwb + (size_t)(K0) * 256;                             \
        char*       al = (char*)&Alds[BUF][0];                                 \
        GLD16(at + wave * 1024 + lane * 16, al + wave * 1024);                 \
        char* bl = (char*)&Blds[BUF][0];                                       \
        _Pragma("unroll")                                                      \
        for (int g = 0; g < 2; ++g) {                                          \
            const int gi = wave * 2 + g;              /* 0..15 */              \
            const int r  = gi * 2 + brsel;            /* row 0..31 */          \
            GLD16(xbb + (size_t)((K0) + r) * (HW * 4) + bcol * 16,             \
                  bl + gi * 1024);                                             \
        }                                                                      \
    }

        __syncthreads();   // protect LDS reuse across jobs (aligns barrier phases)
        STAGE(0, 0)

        int cur = 0;
        for (int it = 0; it < NIT; ++it) {
            __syncthreads();   // buf[cur] complete; prior reads of buf[cur^1] done

            if (it + 1 < NIT) STAGE((it + 1) * BK, cur ^ 1)

            // A fragments: 4x ds_read_b128
            bf16x8 af[4];
            #pragma unroll
            for (int tm = 0; tm < 4; ++tm)
                af[tm] = *(const bf16x8*)&Alds[cur][(quad * COUT + wm + tm * 16 + l15) * 8];

            // B fragments: 16x ds_read_b32 + RNE convert
            bf16x8 bfr[2];
            #pragma unroll
            for (int tn = 0; tn < 2; ++tn) {
                union { unsigned short us[8]; bf16x8 v; } pk;
                #pragma unroll
                for (int j = 0; j < 8; ++j)
                    pk.us[j] = f2bf_bits(Blds[cur][(quad * 8 + j) * BN + wn + tn * 16 + l15]);
                bfr[tn] = pk.v;
            }

            #pragma unroll
            for (int tm = 0; tm < 4; ++tm)
                #pragma unroll
                for (int tn = 0; tn < 2; ++tn)
                    acc[tm][tn] = __builtin_amdgcn_mfma_f32_16x16x32_bf16(
                        af[tm], bfr[tn], acc[tm][tn], 0, 0, 0);

            cur ^= 1;
        }
#undef STAGE

        // epilogue: C/D layout col(n)=l15, row(o)=quad*4+reg
        #pragma unroll
        for (int tm = 0; tm < 4; ++tm) {
            const int o = wm + tm * 16 + quad * 4;
            #pragma unroll
            for (int tn = 0; tn < 2; ++tn) {
                const int n = wn + tn * 16 + l15;
                #pragma unroll
                for (int r = 0; r < 4; ++r)
                    outb[(size_t)(o + r) * HW + n] = acc[tm][tn][r];
            }
        }
    }
}

extern "C" void kernel_launch(void* const* d_in, const int* in_sizes, int n_in,
                              void* d_out, int out_size, void* d_ws, size_t ws_size,
                              hipStream_t stream) {
    const float* x      = (const float*)d_in[0];   // (16, 512, 64, 64) fp32
    const float* style  = (const float*)d_in[1];   // (16, 512) fp32
    const float* weight = (const float*)d_in[2];   // (128, 512) fp32
    float* out = (float*)d_out;                    // (16, 128, 64, 64) fp32
    __bf16* mw = (__bf16*)d_ws;                    // 2 MB modulated weights

    modw_kernel<<<dim3(512), dim3(256), 0, stream>>>(style, weight, mw);
    modconv1x1_kernel<<<dim3(256), dim3(512), 0, stream>>>(x, mw, out);
}